// Round 1
// 409.911 us; speedup vs baseline: 1.0856x; 1.0856x over previous
//
#include <hip/hip_runtime.h>
#include <stdint.h>

// ---------------------------------------------------------------------------
// QuantLinear:  Y[n,m] = cs[n]*rs[m]*( Sint[n,m] - zp[n]*Wsum[m] ) + b[m]
// R3: GEMM rewritten as 256x256 deep-pipelined schedule (T1+T2+T3/T4+T5):
//   - BK=128B (4 k-slices of mfma_i32_32x32x32_i8), 8 waves (2n x 4m),
//     per-wave 128(n)x64(m) via 4x2 frags. __launch_bounds__(512,2).
//   - LDS 128KB: 2 buffers x {A,B} x {K-lo,K-hi} 16KB regions, 64B rows,
//     XOR swizzle chunk^( (row>>1)&3 ) applied on pre-swizzled global src
//     (global_load_lds writes linearly) and again at ds_read -> 8 touches/bank.
//   - K-half staging regions retire mid-tile -> 1.5-tile prefetch lead is
//     race-free in a 2-deep buffer; every boundary waits vmcnt(8) (never 0),
//     ONE s_barrier per half-K-tile.
//   - s_setprio(1) around MFMA cluster; XCD-bijective block swizzle (512%8==0).
// Quant kernel unchanged (isolate the GEMM delta; measure quant by subtraction).
// ---------------------------------------------------------------------------

typedef __attribute__((ext_vector_type(4)))  int int4v;
typedef __attribute__((ext_vector_type(16))) int int16v;

__device__ __forceinline__ void async_load16(const void* g, void* l) {
    // global -> LDS DMA, 16B/lane; LDS dest = wave-uniform base + lane*16.
    __builtin_amdgcn_global_load_lds(
        (const __attribute__((address_space(1))) void*)g,
        (__attribute__((address_space(3))) void*)l, 16, 0, 0);
}

__device__ __forceinline__ int quant_clip(float v) {
    // matches np: clip(rint(v), -128, 127); rintf = round-half-even
    return (int)fminf(fmaxf(rintf(v), -128.f), 127.f);
}

// ---------------------------------------------------------------------------
// Merged quant kernel (unchanged from R2). Blocks [0,M) quantize W rows;
// blocks [M,M+N) quantize X token-rows. 256 threads, 4 x float4 per thread.
// ---------------------------------------------------------------------------
__global__ __launch_bounds__(256) void quant_kernel(
    const float* __restrict__ W, const float* __restrict__ X,
    int8_t* __restrict__ Wq, int8_t* __restrict__ Xq,
    float* __restrict__ row_scale, int* __restrict__ wsum,
    float* __restrict__ col_scale, int* __restrict__ zp, int M, int K) {
    const int blk  = blockIdx.x;
    const int tid  = threadIdx.x;
    const int lane = tid & 63;
    const int wv   = tid >> 6;
    __shared__ float sred0[4], sred1[4];
    __shared__ int   isum[4];

    if (blk < M) {
        const int row = blk;
        const float4* w4 = (const float4*)(W + (size_t)row * K);
        float4 vals[4];
        float amax = 0.f;
#pragma unroll
        for (int i = 0; i < 4; ++i) {
            float4 v = w4[tid + i * 256];
            vals[i] = v;
            amax = fmaxf(amax, fmaxf(fmaxf(fabsf(v.x), fabsf(v.y)),
                                     fmaxf(fabsf(v.z), fabsf(v.w))));
        }
#pragma unroll
        for (int off = 32; off > 0; off >>= 1)
            amax = fmaxf(amax, __shfl_down(amax, off, 64));
        if (lane == 0) sred0[wv] = amax;
        __syncthreads();
        amax = fmaxf(fmaxf(sred0[0], sred0[1]), fmaxf(sred0[2], sred0[3]));

        const float scale = (amax > 0.f) ? (amax / 127.f) : 1.f;
        const float inv   = 1.f / scale;

        int ssum = 0;
        int* wq32 = (int*)(Wq + (size_t)row * K);
#pragma unroll
        for (int i = 0; i < 4; ++i) {
            float4 v = vals[i];
            int q0 = quant_clip(v.x * inv);
            int q1 = quant_clip(v.y * inv);
            int q2 = quant_clip(v.z * inv);
            int q3 = quant_clip(v.w * inv);
            ssum += q0 + q1 + q2 + q3;
            wq32[tid + i * 256] =
                (q0 & 0xff) | ((q1 & 0xff) << 8) | ((q2 & 0xff) << 16) | ((q3 & 0xff) << 24);
        }
#pragma unroll
        for (int off = 32; off > 0; off >>= 1)
            ssum += __shfl_down(ssum, off, 64);
        if (lane == 0) isum[wv] = ssum;
        __syncthreads();
        if (tid == 0) {
            wsum[row] = isum[0] + isum[1] + isum[2] + isum[3];
            row_scale[row] = scale;
        }
    } else {
        const int row = blk - M;
        const float4* x4 = (const float4*)(X + (size_t)row * K);
        float4 vals[4];
        float vmin = 3.402823466e+38f, vmax = -3.402823466e+38f;
#pragma unroll
        for (int i = 0; i < 4; ++i) {
            float4 v = x4[tid + i * 256];
            vals[i] = v;
            vmin = fminf(vmin, fminf(fminf(v.x, v.y), fminf(v.z, v.w)));
            vmax = fmaxf(vmax, fmaxf(fmaxf(v.x, v.y), fmaxf(v.z, v.w)));
        }
#pragma unroll
        for (int off = 32; off > 0; off >>= 1) {
            vmin = fminf(vmin, __shfl_down(vmin, off, 64));
            vmax = fmaxf(vmax, __shfl_down(vmax, off, 64));
        }
        if (lane == 0) { sred0[wv] = vmin; sred1[wv] = vmax; }
        __syncthreads();
        vmin = fminf(fminf(sred0[0], sred0[1]), fminf(sred0[2], sred0[3]));
        vmax = fmaxf(fmaxf(sred1[0], sred1[1]), fmaxf(sred1[2], sred1[3]));

        const float rng   = vmax - vmin;
        const float scale = (rng > 0.f) ? (rng / 255.f) : 1.f;
        const float inv   = 1.f / scale;
        const float zpf   = fminf(fmaxf(rintf(-128.f - vmin * inv), -128.f), 127.f);

        int* xq32 = (int*)(Xq + (size_t)row * K);
#pragma unroll
        for (int i = 0; i < 4; ++i) {
            float4 v = vals[i];
            int q0 = quant_clip(v.x * inv + zpf);
            int q1 = quant_clip(v.y * inv + zpf);
            int q2 = quant_clip(v.z * inv + zpf);
            int q3 = quant_clip(v.w * inv + zpf);
            xq32[tid + i * 256] =
                (q0 & 0xff) | ((q1 & 0xff) << 8) | ((q2 & 0xff) << 16) | ((q3 & 0xff) << 24);
        }
        if (tid == 0) {
            col_scale[row] = scale;
            zp[row] = (int)zpf;
        }
    }
}

// ---------------------------------------------------------------------------
// int8 GEMM, 256x256 tile, deep-pipelined.
//
// LDS regions: REGION(buf, mat, kh) = 16KB = 256 rows x 64B (2 k-slices).
// Row r, logical 16B chunk c stored at physical chunk c ^ ((r>>1)&3).
// Stage of one region = 2 x global_load_lds (row-blocks 0-127 / 128-255);
// each wave covers 16 rows (1KB) at wave-uniform dest + lane*16; the swizzle
// is folded into the per-lane GLOBAL source address.
//
// Schedule per K-tile t (buffer b = t&1), NT = K/128 tiles:
//   P0: issue khi(t+1) -> buf b^1 ; compute k-slices 0,1 from (b, klo)
//       s_waitcnt vmcnt(8) ; s_barrier
//   P1: issue klo(t+2) -> buf b   ; compute k-slices 2,3 from (b, khi)
//       s_waitcnt vmcnt(8) ; s_barrier
// klo(b) is dead after P0, so the klo(t+2) write into buffer b is race-free.
// Accounting (loads, per wave): prologue issues 12; each phase issues 4;
// at the boundary before tile t P0, issued = 12+8t, vmcnt(8) retires through
// load 8t+3 = exactly klo(t); before P1, issued = 12+8t+4, retires khi(t).
// Tail: issues clamped to tile NT-1 (rewrites retired/identical regions).
// ---------------------------------------------------------------------------
#define REGION(buf, mat, kh) (lds + ((((buf) * 2 + (mat)) * 2 + (kh)) << 14))

__device__ __forceinline__ void compute_half(
    const int8_t* Ar, const int8_t* Br,
    const int aoff[4], const int boff[2],
    const int half, const int sw4, int16v (&acc)[4][2]) {
    __builtin_amdgcn_s_setprio(1);
#pragma unroll
    for (int ss = 0; ss < 2; ++ss) {
        const int cc = ((((ss << 1) + half) ^ sw4) << 4);
        int4v a[4], b[2];
#pragma unroll
        for (int i = 0; i < 4; ++i)
            a[i] = *(const int4v*)(Ar + aoff[i] + cc);
#pragma unroll
        for (int j = 0; j < 2; ++j)
            b[j] = *(const int4v*)(Br + boff[j] + cc);
#pragma unroll
        for (int i = 0; i < 4; ++i)
#pragma unroll
            for (int j = 0; j < 2; ++j)
                acc[i][j] = __builtin_amdgcn_mfma_i32_32x32x32_i8(
                    a[i], b[j], acc[i][j], 0, 0, 0);
    }
    __builtin_amdgcn_s_setprio(0);
}

__global__ __launch_bounds__(512, 2) void gemm_i8_kernel(
    const int8_t* __restrict__ Xq, const int8_t* __restrict__ Wq,
    const float* __restrict__ cs, const int* __restrict__ zp,
    const float* __restrict__ rs, const int* __restrict__ wsum,
    const float* __restrict__ bias, float* __restrict__ out,
    int N, int M, int K) {
    __shared__ __align__(16) int8_t lds[131072];  // 128 KB

    const int t    = threadIdx.x;
    const int wv   = t >> 6;       // 0..7
    const int lane = t & 63;
    const int r32  = lane & 31;
    const int half = lane >> 5;
    const int wn   = wv >> 2;      // 0..1  (n-wave)
    const int wm   = wv & 3;       // 0..3  (m-wave)

    // ---- XCD-bijective block swizzle (nwg = 512, % 8 == 0) ----
    const int nMB = M >> 8;                    // 16
    const int per = ((M >> 8) * (N >> 8)) >> 3;  // blocks per XCD = 64
    const int lin = blockIdx.x;
    const int g   = (lin & 7) * per + (lin >> 3);
    const int m0  = (g % nMB) << 8;
    const int n0  = (g / nMB) << 8;

    const int NT = K >> 7;  // K-tiles of 128

    // ---- staging thread mapping: 1KB/wave/load = 16 rows x 64B ----
    // lane l -> row lrow = wv*16 + l/4, physical chunk l&3; the global source
    // supplies logical chunk (l&3) ^ swz(row), swz(row) = (row>>1)&3 = (l>>3)&3.
    const int lrow   = (wv << 4) + (lane >> 2);               // 0..127
    const int srcOff = (((lane & 3) ^ ((lane >> 3) & 3)) << 4);
    const int8_t* gA0 = Xq + (size_t)(n0 + lrow) * K + srcOff;
    const int8_t* gA1 = Xq + (size_t)(n0 + 128 + lrow) * K + srcOff;
    const int8_t* gB0 = Wq + (size_t)(m0 + lrow) * K + srcOff;
    const int8_t* gB1 = Wq + (size_t)(m0 + 128 + lrow) * K + srcOff;
    const int wvOff = wv << 10;

    // ---- reader offsets: rows of the 256x64B region, swizzle on chunk ----
    int aoff[4], boff[2];
#pragma unroll
    for (int i = 0; i < 4; ++i) aoff[i] = (((wn << 7) + i * 32 + r32) << 6);
#pragma unroll
    for (int j = 0; j < 2; ++j) boff[j] = (((wm << 6) + j * 32 + r32) << 6);
    const int sw4 = (r32 >> 1) & 3;  // (row>>1)&3; wave/frag bases are 0 mod 4

    int16v acc[4][2];
#pragma unroll
    for (int i = 0; i < 4; ++i)
#pragma unroll
        for (int j = 0; j < 2; ++j)
            acc[i][j] = (int16v)(0);

    // ---- prologue: klo(0), khi(0), klo(1) = 12 loads/wave ----
    {
        int8_t* r;
        r = REGION(0, 0, 0) + wvOff; async_load16(gA0, r);       async_load16(gA1, r + 8192);
        r = REGION(0, 1, 0) + wvOff; async_load16(gB0, r);       async_load16(gB1, r + 8192);
        r = REGION(0, 0, 1) + wvOff; async_load16(gA0 + 64, r);  async_load16(gA1 + 64, r + 8192);
        r = REGION(0, 1, 1) + wvOff; async_load16(gB0 + 64, r);  async_load16(gB1 + 64, r + 8192);
        r = REGION(1, 0, 0) + wvOff; async_load16(gA0 + 128, r); async_load16(gA1 + 128, r + 8192);
        r = REGION(1, 1, 0) + wvOff; async_load16(gB0 + 128, r); async_load16(gB1 + 128, r + 8192);
    }
    asm volatile("s_waitcnt vmcnt(8)" ::: "memory");  // klo(0) resident
    __builtin_amdgcn_s_barrier();

    // ---- main loop ----
    for (int tt = 0; tt < NT; ++tt) {
        const int buf = tt & 1;
        {   // P0: prefetch khi(t+1) into buf^1; compute k-slices 0,1
            const int tn = (tt + 1 < NT) ? tt + 1 : NT - 1;  // clamped tail
            const int ko = (tn << 7) + 64;
            int8_t* r;
            r = REGION(buf ^ 1, 0, 1) + wvOff;
            async_load16(gA0 + ko, r); async_load16(gA1 + ko, r + 8192);
            r = REGION(buf ^ 1, 1, 1) + wvOff;
            async_load16(gB0 + ko, r); async_load16(gB1 + ko, r + 8192);

            compute_half(REGION(buf, 0, 0), REGION(buf, 1, 0), aoff, boff, half, sw4, acc);

            asm volatile("s_waitcnt vmcnt(8)" ::: "memory");  // khi(tt) resident
            __builtin_amdgcn_s_barrier();
        }
        {   // P1: prefetch klo(t+2) into buf (klo retired after P0); compute k-slices 2,3
            const int tn = (tt + 2 < NT) ? tt + 2 : NT - 1;  // clamped tail
            const int ko = (tn << 7);
            int8_t* r;
            r = REGION(buf, 0, 0) + wvOff;
            async_load16(gA0 + ko, r); async_load16(gA1 + ko, r + 8192);
            r = REGION(buf, 1, 0) + wvOff;
            async_load16(gB0 + ko, r); async_load16(gB1 + ko, r + 8192);

            compute_half(REGION(buf, 0, 1), REGION(buf, 1, 1), aoff, boff, half, sw4, acc);

            asm volatile("s_waitcnt vmcnt(8)" ::: "memory");  // klo(tt+1) resident
            __builtin_amdgcn_s_barrier();
        }
    }

    // ---- epilogue: 32x32 C/D: col(m)=lane&31, row(n)=(reg&3)+8*(reg>>2)+4*half
    int   mm[2];
    float rsv[2], bv[2];
    int   wsv[2];
#pragma unroll
    for (int j = 0; j < 2; ++j) {
        mm[j]  = m0 + (wm << 6) + j * 32 + r32;
        rsv[j] = rs[mm[j]];
        bv[j]  = bias[mm[j]];
        wsv[j] = wsum[mm[j]];
    }
#pragma unroll
    for (int i = 0; i < 4; ++i) {
        const int nbase = n0 + (wn << 7) + i * 32 + (half << 2);
#pragma unroll
        for (int reg = 0; reg < 16; ++reg) {
            const int n = nbase + (reg & 3) + 8 * (reg >> 2);
            const float csn = cs[n];
            const int   zpn = zp[n];
#pragma unroll
            for (int j = 0; j < 2; ++j) {
                const int ival = acc[i][j][reg] - zpn * wsv[j];
                out[(size_t)n * M + mm[j]] = csn * rsv[j] * (float)ival + bv[j];
            }
        }
    }
}

// ---------------------------------------------------------------------------
extern "C" void kernel_launch(void* const* d_in, const int* in_sizes, int n_in,
                              void* d_out, int out_size, void* d_ws, size_t ws_size,
                              hipStream_t stream) {
    const float* x = (const float*)d_in[0];
    const float* W = (const float*)d_in[1];
    const float* b = (const float*)d_in[2];
    float* out = (float*)d_out;

    const int M = in_sizes[2];            // 4096
    const int K = in_sizes[1] / M;        // 4096
    const int N = in_sizes[0] / K;        // 8192

    // workspace carve-up (~50.4 MB)
    int8_t* Xq = (int8_t*)d_ws;                       // N*K
    int8_t* Wq = Xq + (size_t)N * K;                  // M*K
    float* cs  = (float*)(Wq + (size_t)M * K);        // N
    int* zps   = (int*)(cs + N);                      // N
    float* rs  = (float*)(zps + N);                   // M
    int* wsum  = (int*)(rs + M);                      // M

    quant_kernel<<<dim3(M + N), dim3(256), 0, stream>>>(
        W, x, Wq, Xq, rs, wsum, cs, zps, M, K);
    gemm_i8_kernel<<<dim3((M >> 8) * (N >> 8)), dim3(512), 0, stream>>>(
        Xq, Wq, cs, zps, rs, wsum, b, out, N, M, K);
}

// Round 2
// 405.930 us; speedup vs baseline: 1.0963x; 1.0098x over previous
//
#include <hip/hip_runtime.h>
#include <stdint.h>

// ---------------------------------------------------------------------------
// QuantLinear:  Y[n,m] = cs[n]*rs[m]*( Sint[n,m] - zp[n]*Wsum[m] ) + b[m]
// R4: same 256x256 / 8-wave / BK=128 geometry as R3, but the K-loop is
// restructured into the m201 4-phase discipline:
//   phase p: { ds_read slice p+1 (6 x b128, into spare reg set)
//              | 2 x global_load_lds stage }
//            -> s_barrier -> sched_barrier(0)
//            -> setprio(1) ; 8 x mfma_i32_32x32x32_i8 (slice p) ; setprio(0)
//            -> [vmcnt(6) at phases 0,2]  -> s_barrier
// Reads are pipelined ONE slice ahead, so each phase's LDS traffic drains
// under the previous slice's MFMA cluster (compiler emits counted lgkmcnt(6)
// for the 6-older consumed set). vmcnt is always counted (6), never 0.
// Bank-conflict counter ~4/b128 is the structural b128 floor (m134) - ignored.
// Quant kernel unchanged.
// ---------------------------------------------------------------------------

typedef __attribute__((ext_vector_type(4)))  int int4v;
typedef __attribute__((ext_vector_type(16))) int int16v;

__device__ __forceinline__ void async_load16(const void* g, void* l) {
    __builtin_amdgcn_global_load_lds(
        (const __attribute__((address_space(1))) void*)g,
        (__attribute__((address_space(3))) void*)l, 16, 0, 0);
}

__device__ __forceinline__ int quant_clip(float v) {
    // matches np: clip(rint(v), -128, 127); rintf = round-half-even
    return (int)fminf(fmaxf(rintf(v), -128.f), 127.f);
}

// ---------------------------------------------------------------------------
// Merged quant kernel (unchanged). Blocks [0,M) quantize W rows; blocks
// [M,M+N) quantize X token-rows. 256 threads, 4 x float4 per thread.
// ---------------------------------------------------------------------------
__global__ __launch_bounds__(256) void quant_kernel(
    const float* __restrict__ W, const float* __restrict__ X,
    int8_t* __restrict__ Wq, int8_t* __restrict__ Xq,
    float* __restrict__ row_scale, int* __restrict__ wsum,
    float* __restrict__ col_scale, int* __restrict__ zp, int M, int K) {
    const int blk  = blockIdx.x;
    const int tid  = threadIdx.x;
    const int lane = tid & 63;
    const int wv   = tid >> 6;
    __shared__ float sred0[4], sred1[4];
    __shared__ int   isum[4];

    if (blk < M) {
        const int row = blk;
        const float4* w4 = (const float4*)(W + (size_t)row * K);
        float4 vals[4];
        float amax = 0.f;
#pragma unroll
        for (int i = 0; i < 4; ++i) {
            float4 v = w4[tid + i * 256];
            vals[i] = v;
            amax = fmaxf(amax, fmaxf(fmaxf(fabsf(v.x), fabsf(v.y)),
                                     fmaxf(fabsf(v.z), fabsf(v.w))));
        }
#pragma unroll
        for (int off = 32; off > 0; off >>= 1)
            amax = fmaxf(amax, __shfl_down(amax, off, 64));
        if (lane == 0) sred0[wv] = amax;
        __syncthreads();
        amax = fmaxf(fmaxf(sred0[0], sred0[1]), fmaxf(sred0[2], sred0[3]));

        const float scale = (amax > 0.f) ? (amax / 127.f) : 1.f;
        const float inv   = 1.f / scale;

        int ssum = 0;
        int* wq32 = (int*)(Wq + (size_t)row * K);
#pragma unroll
        for (int i = 0; i < 4; ++i) {
            float4 v = vals[i];
            int q0 = quant_clip(v.x * inv);
            int q1 = quant_clip(v.y * inv);
            int q2 = quant_clip(v.z * inv);
            int q3 = quant_clip(v.w * inv);
            ssum += q0 + q1 + q2 + q3;
            wq32[tid + i * 256] =
                (q0 & 0xff) | ((q1 & 0xff) << 8) | ((q2 & 0xff) << 16) | ((q3 & 0xff) << 24);
        }
#pragma unroll
        for (int off = 32; off > 0; off >>= 1)
            ssum += __shfl_down(ssum, off, 64);
        if (lane == 0) isum[wv] = ssum;
        __syncthreads();
        if (tid == 0) {
            wsum[row] = isum[0] + isum[1] + isum[2] + isum[3];
            row_scale[row] = scale;
        }
    } else {
        const int row = blk - M;
        const float4* x4 = (const float4*)(X + (size_t)row * K);
        float4 vals[4];
        float vmin = 3.402823466e+38f, vmax = -3.402823466e+38f;
#pragma unroll
        for (int i = 0; i < 4; ++i) {
            float4 v = x4[tid + i * 256];
            vals[i] = v;
            vmin = fminf(vmin, fminf(fminf(v.x, v.y), fminf(v.z, v.w)));
            vmax = fmaxf(vmax, fmaxf(fmaxf(v.x, v.y), fmaxf(v.z, v.w)));
        }
#pragma unroll
        for (int off = 32; off > 0; off >>= 1) {
            vmin = fminf(vmin, __shfl_down(vmin, off, 64));
            vmax = fmaxf(vmax, __shfl_down(vmax, off, 64));
        }
        if (lane == 0) { sred0[wv] = vmin; sred1[wv] = vmax; }
        __syncthreads();
        vmin = fminf(fminf(sred0[0], sred0[1]), fminf(sred0[2], sred0[3]));
        vmax = fmaxf(fmaxf(sred1[0], sred1[1]), fmaxf(sred1[2], sred1[3]));

        const float rng   = vmax - vmin;
        const float scale = (rng > 0.f) ? (rng / 255.f) : 1.f;
        const float inv   = 1.f / scale;
        const float zpf   = fminf(fmaxf(rintf(-128.f - vmin * inv), -128.f), 127.f);

        int* xq32 = (int*)(Xq + (size_t)row * K);
#pragma unroll
        for (int i = 0; i < 4; ++i) {
            float4 v = vals[i];
            int q0 = quant_clip(v.x * inv + zpf);
            int q1 = quant_clip(v.y * inv + zpf);
            int q2 = quant_clip(v.z * inv + zpf);
            int q3 = quant_clip(v.w * inv + zpf);
            xq32[tid + i * 256] =
                (q0 & 0xff) | ((q1 & 0xff) << 8) | ((q2 & 0xff) << 16) | ((q3 & 0xff) << 24);
        }
        if (tid == 0) {
            col_scale[row] = scale;
            zp[row] = (int)zpf;
        }
    }
}

// ---------------------------------------------------------------------------
// int8 GEMM, 256x256 tile, 4-phase-per-K-tile pipelined schedule.
//
// LDS regions: REGION(buf, mat, kh) = 16KB = 256 rows x 64B (2 k-slices).
// Row r, logical 16B chunk c stored at physical chunk c ^ ((r>>1)&3); the
// XOR is folded into the per-lane GLOBAL source address at staging time
// (global_load_lds dest is linear), and applied again at ds_read time.
//
// Per K-tile t (buf = t&1), slices 0,1 in kh=0, slices 2,3 in kh=1:
//   ph0: read slice1(lo)      | stage khi(t+1)[A] -> buf^1 | B | MFMA s0 | vm6 | B
//   ph1: read slice2(hi)      | stage khi(t+1)[B] -> buf^1 | B | MFMA s1 |     | B
//   ph2: read slice3(hi)      | stage klo(t+2)[A] -> buf   | B | MFMA s2 | vm6 | B
//   ph3: read slice0(t+1, lo) | stage klo(t+2)[B] -> buf   | B | MFMA s3 |     | B
// vmcnt(6) accounting (2 loads issued/phase): guard khi(t) before ph1 reads:
// since khi(t) issued (t-1 ph0,1): t-1 ph2,3 + t ph0 = 6 outstanding. Guard
// klo(t+1) before ph3 reads: since its issue (t-1 ph2,3): t ph0,1,2 = 6.
// Region-overwrite safety: every staged write is issued >=2 barriers after
// the last ds_read of its region, and those reads are lgkm-retired before
// the MFMA cluster preceding the releasing barrier.
// ---------------------------------------------------------------------------
#define REGION(buf, mat, kh) (lds + ((((buf) * 2 + (mat)) * 2 + (kh)) << 14))

__device__ __forceinline__ void read6(int4v (&a)[4], int4v (&b)[2],
                                      const int8_t* Ar, const int8_t* Br,
                                      const int aoff[4], const int boff[2],
                                      const int cc) {
#pragma unroll
    for (int i = 0; i < 4; ++i) a[i] = *(const int4v*)(Ar + aoff[i] + cc);
#pragma unroll
    for (int j = 0; j < 2; ++j) b[j] = *(const int4v*)(Br + boff[j] + cc);
}

__device__ __forceinline__ void mfma8(const int4v (&a)[4], const int4v (&b)[2],
                                      int16v (&acc)[4][2]) {
    __builtin_amdgcn_s_setprio(1);
#pragma unroll
    for (int i = 0; i < 4; ++i)
#pragma unroll
        for (int j = 0; j < 2; ++j)
            acc[i][j] = __builtin_amdgcn_mfma_i32_32x32x32_i8(
                a[i], b[j], acc[i][j], 0, 0, 0);
    __builtin_amdgcn_s_setprio(0);
}

__global__ __launch_bounds__(512, 2) void gemm_i8_kernel(
    const int8_t* __restrict__ Xq, const int8_t* __restrict__ Wq,
    const float* __restrict__ cs, const int* __restrict__ zp,
    const float* __restrict__ rs, const int* __restrict__ wsum,
    const float* __restrict__ bias, float* __restrict__ out,
    int N, int M, int K) {
    __shared__ __align__(16) int8_t lds[131072];  // 128 KB

    const int t    = threadIdx.x;
    const int wv   = t >> 6;       // 0..7
    const int lane = t & 63;
    const int r32  = lane & 31;
    const int half = lane >> 5;
    const int wn   = wv >> 2;      // 0..1  (n-wave)
    const int wm   = wv & 3;       // 0..3  (m-wave)

    // ---- XCD-bijective block swizzle (nwg = 512, % 8 == 0) ----
    const int nMB = M >> 8;                      // 16
    const int per = ((M >> 8) * (N >> 8)) >> 3;  // blocks per XCD = 64
    const int lin = blockIdx.x;
    const int g   = (lin & 7) * per + (lin >> 3);
    const int m0  = (g % nMB) << 8;
    const int n0  = (g / nMB) << 8;

    const int NT = K >> 7;  // K-tiles of 128

    // ---- staging map: lane l -> row wv*16 + l/4, phys chunk l&3; global
    // source supplies logical chunk (l&3) ^ ((row>>1)&3) = (l&3)^((l>>3)&3).
    const int lrow   = (wv << 4) + (lane >> 2);               // 0..127
    const int srcOff = (((lane & 3) ^ ((lane >> 3) & 3)) << 4);
    const int8_t* gA0 = Xq + (size_t)(n0 + lrow) * K + srcOff;
    const int8_t* gA1 = Xq + (size_t)(n0 + 128 + lrow) * K + srcOff;
    const int8_t* gB0 = Wq + (size_t)(m0 + lrow) * K + srcOff;
    const int8_t* gB1 = Wq + (size_t)(m0 + 128 + lrow) * K + srcOff;
    const int wvOff = wv << 10;

    // ---- reader offsets: rows of the 256x64B region, swizzle on chunk ----
    int aoff[4], boff[2];
#pragma unroll
    for (int i = 0; i < 4; ++i) aoff[i] = (((wn << 7) + i * 32 + r32) << 6);
#pragma unroll
    for (int j = 0; j < 2; ++j) boff[j] = (((wm << 6) + j * 32 + r32) << 6);
    const int sw4 = (r32 >> 1) & 3;
    const int cc0 = ((half ^ sw4) << 4);        // slice-local ss=0
    const int cc1 = (((2 + half) ^ sw4) << 4);  // slice-local ss=1

    int16v acc[4][2];
#pragma unroll
    for (int i = 0; i < 4; ++i)
#pragma unroll
        for (int j = 0; j < 2; ++j)
            acc[i][j] = (int16v)(0);

    // ---- prologue: stage klo(0), khi(0), klo(1) = 12 loads/wave ----
    {
        int8_t* r;
        r = REGION(0, 0, 0) + wvOff; async_load16(gA0, r);       async_load16(gA1, r + 8192);
        r = REGION(0, 1, 0) + wvOff; async_load16(gB0, r);       async_load16(gB1, r + 8192);
        r = REGION(0, 0, 1) + wvOff; async_load16(gA0 + 64, r);  async_load16(gA1 + 64, r + 8192);
        r = REGION(0, 1, 1) + wvOff; async_load16(gB0 + 64, r);  async_load16(gB1 + 64, r + 8192);
        r = REGION(1, 0, 0) + wvOff; async_load16(gA0 + 128, r); async_load16(gA1 + 128, r + 8192);
        r = REGION(1, 1, 0) + wvOff; async_load16(gB0 + 128, r); async_load16(gB1 + 128, r + 8192);
    }
    asm volatile("s_waitcnt vmcnt(8)" ::: "memory");  // klo(0) resident
    __builtin_amdgcn_s_barrier();

    int4v aA[4], bA[2], aB[4], bB[2];
    // pre-read slice0 of tile 0 into set A
    read6(aA, bA, REGION(0, 0, 0), REGION(0, 1, 0), aoff, boff, cc0);

    for (int tt = 0; tt < NT; ++tt) {
        const int buf = tt & 1;
        const int tn1 = (tt + 1 < NT) ? tt + 1 : NT - 1;
        const int tn2 = (tt + 2 < NT) ? tt + 2 : NT - 1;
        const int ko1 = (tn1 << 7) + 64;
        const int ko2 = (tn2 << 7);
        int8_t* r;

        // ---- ph0: read slice1(lo) -> B; stage khi(t+1)[A]; MFMA slice0(A)
        read6(aB, bB, REGION(buf, 0, 0), REGION(buf, 1, 0), aoff, boff, cc1);
        r = REGION(buf ^ 1, 0, 1) + wvOff;
        async_load16(gA0 + ko1, r); async_load16(gA1 + ko1, r + 8192);
        __builtin_amdgcn_s_barrier();
        __builtin_amdgcn_sched_barrier(0);
        mfma8(aA, bA, acc);
        asm volatile("s_waitcnt vmcnt(6)" ::: "memory");  // khi(t) resident
        __builtin_amdgcn_s_barrier();

        // ---- ph1: read slice2(hi) -> A; stage khi(t+1)[B]; MFMA slice1(B)
        read6(aA, bA, REGION(buf, 0, 1), REGION(buf, 1, 1), aoff, boff, cc0);
        r = REGION(buf ^ 1, 1, 1) + wvOff;
        async_load16(gB0 + ko1, r); async_load16(gB1 + ko1, r + 8192);
        __builtin_amdgcn_s_barrier();
        __builtin_amdgcn_sched_barrier(0);
        mfma8(aB, bB, acc);
        __builtin_amdgcn_s_barrier();

        // ---- ph2: read slice3(hi) -> B; stage klo(t+2)[A]; MFMA slice2(A)
        read6(aB, bB, REGION(buf, 0, 1), REGION(buf, 1, 1), aoff, boff, cc1);
        r = REGION(buf, 0, 0) + wvOff;
        async_load16(gA0 + ko2, r); async_load16(gA1 + ko2, r + 8192);
        __builtin_amdgcn_s_barrier();
        __builtin_amdgcn_sched_barrier(0);
        mfma8(aA, bA, acc);
        asm volatile("s_waitcnt vmcnt(6)" ::: "memory");  // klo(t+1) resident
        __builtin_amdgcn_s_barrier();

        // ---- ph3: read slice0(t+1, lo, buf^1) -> A; stage klo(t+2)[B]; MFMA slice3(B)
        read6(aA, bA, REGION(buf ^ 1, 0, 0), REGION(buf ^ 1, 1, 0), aoff, boff, cc0);
        r = REGION(buf, 1, 0) + wvOff;
        async_load16(gB0 + ko2, r); async_load16(gB1 + ko2, r + 8192);
        __builtin_amdgcn_s_barrier();
        __builtin_amdgcn_sched_barrier(0);
        mfma8(aB, bB, acc);
        __builtin_amdgcn_s_barrier();
    }

    // ---- epilogue: 32x32 C/D: col(m)=lane&31, row(n)=(reg&3)+8*(reg>>2)+4*half
    int   mm[2];
    float rsv[2], bv[2];
    int   wsv[2];
#pragma unroll
    for (int j = 0; j < 2; ++j) {
        mm[j]  = m0 + (wm << 6) + j * 32 + r32;
        rsv[j] = rs[mm[j]];
        bv[j]  = bias[mm[j]];
        wsv[j] = wsum[mm[j]];
    }
#pragma unroll
    for (int i = 0; i < 4; ++i) {
        const int nbase = n0 + (wn << 7) + i * 32 + (half << 2);
#pragma unroll
        for (int reg = 0; reg < 16; ++reg) {
            const int n = nbase + (reg & 3) + 8 * (reg >> 2);
            const float csn = cs[n];
            const int   zpn = zp[n];
#pragma unroll
            for (int j = 0; j < 2; ++j) {
                const int ival = acc[i][j][reg] - zpn * wsv[j];
                out[(size_t)n * M + mm[j]] = csn * rsv[j] * (float)ival + bv[j];
            }
        }
    }
}

// ---------------------------------------------------------------------------
extern "C" void kernel_launch(void* const* d_in, const int* in_sizes, int n_in,
                              void* d_out, int out_size, void* d_ws, size_t ws_size,
                              hipStream_t stream) {
    const float* x = (const float*)d_in[0];
    const float* W = (const float*)d_in[1];
    const float* b = (const float*)d_in[2];
    float* out = (float*)d_out;

    const int M = in_sizes[2];            // 4096
    const int K = in_sizes[1] / M;        // 4096
    const int N = in_sizes[0] / K;        // 8192

    // workspace carve-up (~50.4 MB)
    int8_t* Xq = (int8_t*)d_ws;                       // N*K
    int8_t* Wq = Xq + (size_t)N * K;                  // M*K
    float* cs  = (float*)(Wq + (size_t)M * K);        // N
    int* zps   = (int*)(cs + N);                      // N
    float* rs  = (float*)(zps + N);                   // M
    int* wsum  = (int*)(rs + M);                      // M

    quant_kernel<<<dim3(M + N), dim3(256), 0, stream>>>(
        W, x, Wq, Xq, rs, wsum, cs, zps, M, K);
    gemm_i8_kernel<<<dim3((M >> 8) * (N >> 8)), dim3(512), 0, stream>>>(
        Xq, Wq, cs, zps, rs, wsum, b, out, N, M, K);
}

// Round 3
// 403.236 us; speedup vs baseline: 1.1036x; 1.0067x over previous
//
#include <hip/hip_runtime.h>
#include <stdint.h>

// ---------------------------------------------------------------------------
// QuantLinear:  Y[n,m] = cs[n]*rs[m]*( Sint[n,m] - zp[n]*Wsum[m] ) + b[m]
// R5: identical to R4 except the LDS swizzle involution.
//   R2-R4 used phys_chunk = c ^ ((row>>1)&3): under the 64-bank/16-lane LDS
//   model (256 B/clk per rocminfo), rows {r,r+4,r+8,r+12} share one 16-bank
//   window and (r>>1)&3 takes only 2 values there -> structural 2-way
//   conflict (= the measured 4 cy/read). Fix: phys_chunk = c ^ ((row>>2)&3),
//   bijective over the window. Applied BOTH at the pre-swizzled global source
//   (rule #21) and at ds_read.
// Schedule (unchanged from R4): 4-phase-per-K-tile, read-one-slice-ahead,
// counted vmcnt(6), setprio around MFMA, XCD-bijective block swizzle.
// ---------------------------------------------------------------------------

typedef __attribute__((ext_vector_type(4)))  int int4v;
typedef __attribute__((ext_vector_type(16))) int int16v;

__device__ __forceinline__ void async_load16(const void* g, void* l) {
    __builtin_amdgcn_global_load_lds(
        (const __attribute__((address_space(1))) void*)g,
        (__attribute__((address_space(3))) void*)l, 16, 0, 0);
}

__device__ __forceinline__ int quant_clip(float v) {
    // matches np: clip(rint(v), -128, 127); rintf = round-half-even
    return (int)fminf(fmaxf(rintf(v), -128.f), 127.f);
}

// ---------------------------------------------------------------------------
// Merged quant kernel (unchanged). Blocks [0,M) quantize W rows; blocks
// [M,M+N) quantize X token-rows. 256 threads, 4 x float4 per thread.
// ---------------------------------------------------------------------------
__global__ __launch_bounds__(256) void quant_kernel(
    const float* __restrict__ W, const float* __restrict__ X,
    int8_t* __restrict__ Wq, int8_t* __restrict__ Xq,
    float* __restrict__ row_scale, int* __restrict__ wsum,
    float* __restrict__ col_scale, int* __restrict__ zp, int M, int K) {
    const int blk  = blockIdx.x;
    const int tid  = threadIdx.x;
    const int lane = tid & 63;
    const int wv   = tid >> 6;
    __shared__ float sred0[4], sred1[4];
    __shared__ int   isum[4];

    if (blk < M) {
        const int row = blk;
        const float4* w4 = (const float4*)(W + (size_t)row * K);
        float4 vals[4];
        float amax = 0.f;
#pragma unroll
        for (int i = 0; i < 4; ++i) {
            float4 v = w4[tid + i * 256];
            vals[i] = v;
            amax = fmaxf(amax, fmaxf(fmaxf(fabsf(v.x), fabsf(v.y)),
                                     fmaxf(fabsf(v.z), fabsf(v.w))));
        }
#pragma unroll
        for (int off = 32; off > 0; off >>= 1)
            amax = fmaxf(amax, __shfl_down(amax, off, 64));
        if (lane == 0) sred0[wv] = amax;
        __syncthreads();
        amax = fmaxf(fmaxf(sred0[0], sred0[1]), fmaxf(sred0[2], sred0[3]));

        const float scale = (amax > 0.f) ? (amax / 127.f) : 1.f;
        const float inv   = 1.f / scale;

        int ssum = 0;
        int* wq32 = (int*)(Wq + (size_t)row * K);
#pragma unroll
        for (int i = 0; i < 4; ++i) {
            float4 v = vals[i];
            int q0 = quant_clip(v.x * inv);
            int q1 = quant_clip(v.y * inv);
            int q2 = quant_clip(v.z * inv);
            int q3 = quant_clip(v.w * inv);
            ssum += q0 + q1 + q2 + q3;
            wq32[tid + i * 256] =
                (q0 & 0xff) | ((q1 & 0xff) << 8) | ((q2 & 0xff) << 16) | ((q3 & 0xff) << 24);
        }
#pragma unroll
        for (int off = 32; off > 0; off >>= 1)
            ssum += __shfl_down(ssum, off, 64);
        if (lane == 0) isum[wv] = ssum;
        __syncthreads();
        if (tid == 0) {
            wsum[row] = isum[0] + isum[1] + isum[2] + isum[3];
            row_scale[row] = scale;
        }
    } else {
        const int row = blk - M;
        const float4* x4 = (const float4*)(X + (size_t)row * K);
        float4 vals[4];
        float vmin = 3.402823466e+38f, vmax = -3.402823466e+38f;
#pragma unroll
        for (int i = 0; i < 4; ++i) {
            float4 v = x4[tid + i * 256];
            vals[i] = v;
            vmin = fminf(vmin, fminf(fminf(v.x, v.y), fminf(v.z, v.w)));
            vmax = fmaxf(vmax, fmaxf(fmaxf(v.x, v.y), fmaxf(v.z, v.w)));
        }
#pragma unroll
        for (int off = 32; off > 0; off >>= 1) {
            vmin = fminf(vmin, __shfl_down(vmin, off, 64));
            vmax = fmaxf(vmax, __shfl_down(vmax, off, 64));
        }
        if (lane == 0) { sred0[wv] = vmin; sred1[wv] = vmax; }
        __syncthreads();
        vmin = fminf(fminf(sred0[0], sred0[1]), fminf(sred0[2], sred0[3]));
        vmax = fmaxf(fmaxf(sred1[0], sred1[1]), fmaxf(sred1[2], sred1[3]));

        const float rng   = vmax - vmin;
        const float scale = (rng > 0.f) ? (rng / 255.f) : 1.f;
        const float inv   = 1.f / scale;
        const float zpf   = fminf(fmaxf(rintf(-128.f - vmin * inv), -128.f), 127.f);

        int* xq32 = (int*)(Xq + (size_t)row * K);
#pragma unroll
        for (int i = 0; i < 4; ++i) {
            float4 v = vals[i];
            int q0 = quant_clip(v.x * inv + zpf);
            int q1 = quant_clip(v.y * inv + zpf);
            int q2 = quant_clip(v.z * inv + zpf);
            int q3 = quant_clip(v.w * inv + zpf);
            xq32[tid + i * 256] =
                (q0 & 0xff) | ((q1 & 0xff) << 8) | ((q2 & 0xff) << 16) | ((q3 & 0xff) << 24);
        }
        if (tid == 0) {
            col_scale[row] = scale;
            zp[row] = (int)zpf;
        }
    }
}

// ---------------------------------------------------------------------------
// int8 GEMM, 256x256 tile, 4-phase-per-K-tile pipelined schedule.
//
// LDS regions: REGION(buf, mat, kh) = 16KB = 256 rows x 64B (2 k-slices).
// Row r, logical 16B chunk c stored at physical chunk c ^ ((r>>2)&3); the
// XOR is folded into the per-lane GLOBAL source address at staging time
// (global_load_lds dest is linear), and applied again at ds_read time.
// Bank analysis (64 banks x 4B, 16 lanes/cy): a 16-lane b128 group covers
// rows r..r+15; rows sharing (r mod 4) share a 16-bank window with 4 chunk
// slots; (r>>2)&3 is bijective over {r,r+4,r+8,r+12} -> conflict-free.
//
// Per K-tile t (buf = t&1), slices 0,1 in kh=0, slices 2,3 in kh=1:
//   ph0: read slice1(lo)      | stage khi(t+1)[A] -> buf^1 | B | MFMA s0 | vm6 | B
//   ph1: read slice2(hi)      | stage khi(t+1)[B] -> buf^1 | B | MFMA s1 |     | B
//   ph2: read slice3(hi)      | stage klo(t+2)[A] -> buf   | B | MFMA s2 | vm6 | B
//   ph3: read slice0(t+1, lo) | stage klo(t+2)[B] -> buf   | B | MFMA s3 |     | B
// vmcnt(6) accounting (2 loads issued/phase): guard khi(t) before ph1 reads:
// since khi(t) issued (t-1 ph0,1): t-1 ph2,3 + t ph0 = 6 outstanding. Guard
// klo(t+1) before ph3 reads: since its issue (t-1 ph2,3): t ph0,1,2 = 6.
// ---------------------------------------------------------------------------
#define REGION(buf, mat, kh) (lds + ((((buf) * 2 + (mat)) * 2 + (kh)) << 14))

__device__ __forceinline__ void read6(int4v (&a)[4], int4v (&b)[2],
                                      const int8_t* Ar, const int8_t* Br,
                                      const int aoff[4], const int boff[2],
                                      const int cc) {
#pragma unroll
    for (int i = 0; i < 4; ++i) a[i] = *(const int4v*)(Ar + aoff[i] + cc);
#pragma unroll
    for (int j = 0; j < 2; ++j) b[j] = *(const int4v*)(Br + boff[j] + cc);
}

__device__ __forceinline__ void mfma8(const int4v (&a)[4], const int4v (&b)[2],
                                      int16v (&acc)[4][2]) {
    __builtin_amdgcn_s_setprio(1);
#pragma unroll
    for (int i = 0; i < 4; ++i)
#pragma unroll
        for (int j = 0; j < 2; ++j)
            acc[i][j] = __builtin_amdgcn_mfma_i32_32x32x32_i8(
                a[i], b[j], acc[i][j], 0, 0, 0);
    __builtin_amdgcn_s_setprio(0);
}

__global__ __launch_bounds__(512, 2) void gemm_i8_kernel(
    const int8_t* __restrict__ Xq, const int8_t* __restrict__ Wq,
    const float* __restrict__ cs, const int* __restrict__ zp,
    const float* __restrict__ rs, const int* __restrict__ wsum,
    const float* __restrict__ bias, float* __restrict__ out,
    int N, int M, int K) {
    __shared__ __align__(16) int8_t lds[131072];  // 128 KB

    const int t    = threadIdx.x;
    const int wv   = t >> 6;       // 0..7
    const int lane = t & 63;
    const int r32  = lane & 31;
    const int half = lane >> 5;
    const int wn   = wv >> 2;      // 0..1  (n-wave)
    const int wm   = wv & 3;       // 0..3  (m-wave)

    // ---- XCD-bijective block swizzle (nwg = 512, % 8 == 0) ----
    const int nMB = M >> 8;                      // 16
    const int per = ((M >> 8) * (N >> 8)) >> 3;  // blocks per XCD = 64
    const int lin = blockIdx.x;
    const int g   = (lin & 7) * per + (lin >> 3);
    const int m0  = (g % nMB) << 8;
    const int n0  = (g / nMB) << 8;

    const int NT = K >> 7;  // K-tiles of 128

    // ---- staging map: lane l -> row wv*16 + l/4, phys chunk l&3; global
    // source supplies logical chunk (l&3) ^ ((row>>2)&3) = (l&3)^((l>>4)&3).
    const int lrow   = (wv << 4) + (lane >> 2);               // 0..127
    const int srcOff = (((lane & 3) ^ ((lane >> 4) & 3)) << 4);
    const int8_t* gA0 = Xq + (size_t)(n0 + lrow) * K + srcOff;
    const int8_t* gA1 = Xq + (size_t)(n0 + 128 + lrow) * K + srcOff;
    const int8_t* gB0 = Wq + (size_t)(m0 + lrow) * K + srcOff;
    const int8_t* gB1 = Wq + (size_t)(m0 + 128 + lrow) * K + srcOff;
    const int wvOff = wv << 10;

    // ---- reader offsets: rows of the 256x64B region, swizzle on chunk ----
    int aoff[4], boff[2];
#pragma unroll
    for (int i = 0; i < 4; ++i) aoff[i] = (((wn << 7) + i * 32 + r32) << 6);
#pragma unroll
    for (int j = 0; j < 2; ++j) boff[j] = (((wm << 6) + j * 32 + r32) << 6);
    const int sw4 = (r32 >> 2) & 3;             // (row>>2)&3; bases are 0 mod 32
    const int cc0 = ((half ^ sw4) << 4);        // slice-local ss=0
    const int cc1 = (((2 + half) ^ sw4) << 4);  // slice-local ss=1

    int16v acc[4][2];
#pragma unroll
    for (int i = 0; i < 4; ++i)
#pragma unroll
        for (int j = 0; j < 2; ++j)
            acc[i][j] = (int16v)(0);

    // ---- prologue: stage klo(0), khi(0), klo(1) = 12 loads/wave ----
    {
        int8_t* r;
        r = REGION(0, 0, 0) + wvOff; async_load16(gA0, r);       async_load16(gA1, r + 8192);
        r = REGION(0, 1, 0) + wvOff; async_load16(gB0, r);       async_load16(gB1, r + 8192);
        r = REGION(0, 0, 1) + wvOff; async_load16(gA0 + 64, r);  async_load16(gA1 + 64, r + 8192);
        r = REGION(0, 1, 1) + wvOff; async_load16(gB0 + 64, r);  async_load16(gB1 + 64, r + 8192);
        r = REGION(1, 0, 0) + wvOff; async_load16(gA0 + 128, r); async_load16(gA1 + 128, r + 8192);
        r = REGION(1, 1, 0) + wvOff; async_load16(gB0 + 128, r); async_load16(gB1 + 128, r + 8192);
    }
    asm volatile("s_waitcnt vmcnt(8)" ::: "memory");  // klo(0) resident
    __builtin_amdgcn_s_barrier();

    int4v aA[4], bA[2], aB[4], bB[2];
    // pre-read slice0 of tile 0 into set A
    read6(aA, bA, REGION(0, 0, 0), REGION(0, 1, 0), aoff, boff, cc0);

    for (int tt = 0; tt < NT; ++tt) {
        const int buf = tt & 1;
        const int tn1 = (tt + 1 < NT) ? tt + 1 : NT - 1;
        const int tn2 = (tt + 2 < NT) ? tt + 2 : NT - 1;
        const int ko1 = (tn1 << 7) + 64;
        const int ko2 = (tn2 << 7);
        int8_t* r;

        // ---- ph0: read slice1(lo) -> B; stage khi(t+1)[A]; MFMA slice0(A)
        read6(aB, bB, REGION(buf, 0, 0), REGION(buf, 1, 0), aoff, boff, cc1);
        r = REGION(buf ^ 1, 0, 1) + wvOff;
        async_load16(gA0 + ko1, r); async_load16(gA1 + ko1, r + 8192);
        __builtin_amdgcn_s_barrier();
        __builtin_amdgcn_sched_barrier(0);
        mfma8(aA, bA, acc);
        asm volatile("s_waitcnt vmcnt(6)" ::: "memory");  // khi(t) resident
        __builtin_amdgcn_s_barrier();

        // ---- ph1: read slice2(hi) -> A; stage khi(t+1)[B]; MFMA slice1(B)
        read6(aA, bA, REGION(buf, 0, 1), REGION(buf, 1, 1), aoff, boff, cc0);
        r = REGION(buf ^ 1, 1, 1) + wvOff;
        async_load16(gB0 + ko1, r); async_load16(gB1 + ko1, r + 8192);
        __builtin_amdgcn_s_barrier();
        __builtin_amdgcn_sched_barrier(0);
        mfma8(aB, bB, acc);
        __builtin_amdgcn_s_barrier();

        // ---- ph2: read slice3(hi) -> B; stage klo(t+2)[A]; MFMA slice2(A)
        read6(aB, bB, REGION(buf, 0, 1), REGION(buf, 1, 1), aoff, boff, cc1);
        r = REGION(buf, 0, 0) + wvOff;
        async_load16(gA0 + ko2, r); async_load16(gA1 + ko2, r + 8192);
        __builtin_amdgcn_s_barrier();
        __builtin_amdgcn_sched_barrier(0);
        mfma8(aA, bA, acc);
        asm volatile("s_waitcnt vmcnt(6)" ::: "memory");  // klo(t+1) resident
        __builtin_amdgcn_s_barrier();

        // ---- ph3: read slice0(t+1, lo, buf^1) -> A; stage klo(t+2)[B]; MFMA slice3(B)
        read6(aA, bA, REGION(buf ^ 1, 0, 0), REGION(buf ^ 1, 1, 0), aoff, boff, cc0);
        r = REGION(buf, 1, 0) + wvOff;
        async_load16(gB0 + ko2, r); async_load16(gB1 + ko2, r + 8192);
        __builtin_amdgcn_s_barrier();
        __builtin_amdgcn_sched_barrier(0);
        mfma8(aB, bB, acc);
        __builtin_amdgcn_s_barrier();
    }

    // ---- epilogue: 32x32 C/D: col(m)=lane&31, row(n)=(reg&3)+8*(reg>>2)+4*half
    int   mm[2];
    float rsv[2], bv[2];
    int   wsv[2];
#pragma unroll
    for (int j = 0; j < 2; ++j) {
        mm[j]  = m0 + (wm << 6) + j * 32 + r32;
        rsv[j] = rs[mm[j]];
        bv[j]  = bias[mm[j]];
        wsv[j] = wsum[mm[j]];
    }
#pragma unroll
    for (int i = 0; i < 4; ++i) {
        const int nbase = n0 + (wn << 7) + i * 32 + (half << 2);
#pragma unroll
        for (int reg = 0; reg < 16; ++reg) {
            const int n = nbase + (reg & 3) + 8 * (reg >> 2);
            const float csn = cs[n];
            const int   zpn = zp[n];
#pragma unroll
            for (int j = 0; j < 2; ++j) {
                const int ival = acc[i][j][reg] - zpn * wsv[j];
                out[(size_t)n * M + mm[j]] = csn * rsv[j] * (float)ival + bv[j];
            }
        }
    }
}

// ---------------------------------------------------------------------------
extern "C" void kernel_launch(void* const* d_in, const int* in_sizes, int n_in,
                              void* d_out, int out_size, void* d_ws, size_t ws_size,
                              hipStream_t stream) {
    const float* x = (const float*)d_in[0];
    const float* W = (const float*)d_in[1];
    const float* b = (const float*)d_in[2];
    float* out = (float*)d_out;

    const int M = in_sizes[2];            // 4096
    const int K = in_sizes[1] / M;        // 4096
    const int N = in_sizes[0] / K;        // 8192

    // workspace carve-up (~50.4 MB)
    int8_t* Xq = (int8_t*)d_ws;                       // N*K
    int8_t* Wq = Xq + (size_t)N * K;                  // M*K
    float* cs  = (float*)(Wq + (size_t)M * K);        // N
    int* zps   = (int*)(cs + N);                      // N
    float* rs  = (float*)(zps + N);                   // M
    int* wsum  = (int*)(rs + M);                      // M

    quant_kernel<<<dim3(M + N), dim3(256), 0, stream>>>(
        W, x, Wq, Xq, rs, wsum, cs, zps, M, K);
    gemm_i8_kernel<<<dim3((M >> 8) * (N >> 8)), dim3(512), 0, stream>>>(
        Xq, Wq, cs, zps, rs, wsum, b, out, N, M, K);
}